// Round 1
// 123.091 us; speedup vs baseline: 1.0183x; 1.0183x over previous
//
#include <hip/hip_runtime.h>
#include <math.h>

#define NBATCH 32
#define S      49152
#define NF     24          // frames (2048 samples each)
#define NB     16          // biquads
#define NBLK   4           // blocks per batch
#define CHUNK  16          // samples per thread
#define NCH    768         // threads per block
#define NWAVE  12          // waves per block
// 4 blocks per batch; block covers 768*16 = 12288 samples = 6 frames.
// R10: wave-granular decoupled prefix chain -- ZERO __syncthreads in the main
// loop. Each wave is a 1024-sample scan partition. Wave w spins on wave w-1's
// per-stage INCLUSIVE affine (LDS, per-stage write-once slots, tag=f+1),
// composes, publishes, proceeds. Batch initial state is zero, so the pred
// inclusive constant IS the incoming state (no fold). Cross-block keeps the
// R6-proven global write-once slots, but publishes the block-INCLUSIVE so the
// consumer reads exactly one slot. Chain latency (47 LDS + 3 L2 hops) is
// pipeline skew, paid once -- not a per-stage barrier-convergence cost.

__device__ __forceinline__ float clampf(float x, float lo, float hi) {
    return fminf(fmaxf(x, lo), hi);
}

// 16 named scalar signal registers -- guaranteed SSA (no alloca; R1-R4 showed
// the allocator pins VGPR at 84 and spills float arrays regardless of hints).
#define FOREACH_S(OP) \
    OP(s00) OP(s01) OP(s02) OP(s03) OP(s04) OP(s05) OP(s06) OP(s07) \
    OP(s08) OP(s09) OP(s10) OP(s11) OP(s12) OP(s13) OP(s14) OP(s15)

#define DECL_S(x) float x;

// Phase A step: state only.  s' = T s + b*x
#define STEPA(x) { \
    const float n1_ = fmaf(t00, ic1, fmaf(t01, ic2, b0 * (x))); \
    const float n2_ = fmaf(t10, ic1, fmaf(t11, ic2, b1 * (x))); \
    ic1 = n1_; ic2 = n2_; }

// Phase C step: output + state.  y = c0*ic1 + c1*ic2 + c2*x, in place.
#define STEPC(x) { \
    const float y_  = fmaf(c0, ic1, fmaf(c1, ic2, c2 * (x))); \
    const float n1_ = fmaf(t00, ic1, fmaf(t01, ic2, b0 * (x))); \
    const float n2_ = fmaf(t10, ic1, fmaf(t11, ic2, b1 * (x))); \
    (x) = y_; ic1 = n1_; ic2 = n2_; }

__global__ __launch_bounds__(NCH, 3)
void biquad_chain_kernel(const float* __restrict__ audio,
                         const float* __restrict__ params,
                         float* __restrict__ out,
                         unsigned int* __restrict__ ws)
{
    __shared__ float sc[NB][NF][16];     // stride 16 -> float4-aligned reads
    __shared__ float sgain[2][NF];       // [0]=in gain, [1]=out gain
    __shared__ float4 sincl[NB][NWAVE][2]; // per-stage per-wave inclusive affine
    __shared__ unsigned int stag[NB][NWAVE]; // per-stage per-wave ready tag

    const int t       = threadIdx.x;
    // XCD co-location swizzle (R8, kept): all 4 quarters of a batch land on
    // blockIdx ≡ xcd (mod 8) -> same XCD, L2-local handshake.
    const int xcd     = blockIdx.x & 7;
    const int slot_   = blockIdx.x >> 3;
    const int bt      = xcd * 4 + (slot_ & 3);   // batch
    const int quarter = slot_ >> 2;              // which quarter of the signal
    const int lane    = t & 63;
    const int wave    = t >> 6;
    const int frame   = quarter * 6 + (wave >> 1);  // 2 waves per 2048-frame

    // ---------------- coefficient init (threads 0..383) ----------------
    if (t < NB * NF) {
        const int f  = t / NF;
        const int fr = t % NF;
        const float* P = params + (size_t)bt * 50 * NF;
        const float fn = P[(3 * f + 0) * NF + fr];
        const float gn = P[(3 * f + 1) * NF + fr];
        const float qn = P[(3 * f + 2) * NF + fr];

        float Q = __expf(-0.69314718f + qn * 3.4657359f);
        Q = clampf(Q, 0.1f, 100.0f);

        float lo, hi;
        int type;                        // 0 hp, 1 lp, 2 peak, 3 lowshelf, 4 highshelf
        if      (f == 0)  { lo = 20.0f;   hi = 500.0f;   type = 0; }
        else if (f == 15) { lo = 5000.0f; hi = 20000.0f; type = 1; }
        else if (f == 1)  { lo = 50.0f;   hi = 16000.0f; type = 3; }
        else if (f == 14) { lo = 50.0f;   hi = 16000.0f; type = 4; }
        else              { lo = 100.0f;  hi = 15000.0f; type = 2; }

        const float fc = __expf(__logf(lo) + fn * (__logf(hi) - __logf(lo)));
        float g_ = __tanf((float)M_PI * fc / 96000.0f);   // angle <= 0.655 rad, safe
        g_ = clampf(g_, 1e-6f, 100.0f);
        const float gdb = -24.0f + 48.0f * gn;

        float a1, a2, a3, m0, m1, m2;
        if (type == 0 || type == 1) {
            const float k = 1.0f / Q;
            a1 = 1.0f / (1.0f + g_ * (g_ + k)); a2 = g_ * a1; a3 = g_ * a2;
            if (type == 0) { m0 = 1.0f; m1 = -k;   m2 = -1.0f; }
            else           { m0 = 0.0f; m1 = 0.0f; m2 = 1.0f;  }
        } else if (type == 2) {
            const float A = __expf(gdb * (2.30258509f / 40.0f));
            const float k = (gdb >= 0.0f) ? 1.0f / (Q * A) : A / Q;
            a1 = 1.0f / (1.0f + g_ * (g_ + k)); a2 = g_ * a1; a3 = g_ * a2;
            m0 = 1.0f; m1 = k * (A * A - 1.0f); m2 = 0.0f;
        } else {
            const float A  = __expf(gdb * (2.30258509f / 40.0f));
            const float sA = sqrtf(A);
            const float k  = 1.0f / Q;
            float gs;
            if (type == 3) gs = (gdb >= 0.0f) ? g_ / sA : g_ * sA;
            else           gs = (gdb >= 0.0f) ? g_ * sA : g_ / sA;
            a1 = 1.0f / (1.0f + gs * (gs + k)); a2 = gs * a1; a3 = gs * a2;
            if (type == 3) { m0 = 1.0f;  m1 = k * (A - 1.0f);      m2 = A * A - 1.0f; }
            else           { m0 = A * A; m1 = k * (1.0f - A) * A;  m2 = 1.0f - A * A; }
        }

        // affine per-sample form: s' = T s + b*x ; y = c0*ic1 + c1*ic2 + c2*x
        const float q2  = a2 * a2 + a3;
        const float t00 = 2.0f * a1 - 1.0f;
        const float t01 = -2.0f * a2;
        const float t10 = 2.0f * a1 * a2;
        const float t11 = 1.0f - 2.0f * q2;
        const float b0  = 2.0f * a2;
        const float b1  = 2.0f * q2;
        const float c0  = a1 * (m1 + m2 * a2);
        const float c1  = m2 * (1.0f - q2) - m1 * a2;
        const float c2  = m0 + m1 * a2 + m2 * q2;

        // M = T^16 by 4 squarings
        float u00 = t00, u01 = t01, u10 = t10, u11 = t11;
        #pragma unroll
        for (int i = 0; i < 4; i++) {
            const float n00 = u00 * u00 + u01 * u10;
            const float n01 = u00 * u01 + u01 * u11;
            const float n10 = u10 * u00 + u11 * u10;
            const float n11 = u10 * u01 + u11 * u11;
            u00 = n00; u01 = n01; u10 = n10; u11 = n11;
        }

        // layout for float4 reads:
        // [0-3]=t00,t01,t10,t11  [4-7]=b0,b1,c0,c1  [8-11]=c2,M00,M01,M10  [12]=M11
        sc[f][fr][0] = t00; sc[f][fr][1] = t01; sc[f][fr][2] = t10; sc[f][fr][3] = t11;
        sc[f][fr][4] = b0;  sc[f][fr][5] = b1;  sc[f][fr][6] = c0;  sc[f][fr][7] = c1;
        sc[f][fr][8] = c2;  sc[f][fr][9] = u00; sc[f][fr][10] = u01; sc[f][fr][11] = u10;
        sc[f][fr][12] = u11;
    }
    if (t >= 384 && t < 384 + 2 * NF) {
        const int idx = t - 384;
        const int which = idx / NF;     // 0 = in gain (row 48), 1 = out gain (row 49)
        const int fr    = idx % NF;
        const float* P = params + (size_t)bt * 50 * NF;
        const float p  = P[(48 + which) * NF + fr];
        const float db = -60.0f + 60.0f * p;
        sgain[which][fr] = __expf(db * (2.30258509f / 20.0f));
    }
    // clear per-stage ready tags (LDS is uninitialized garbage at block start)
    if (t < NB * NWAVE) stag[t / NWAVE][t % NWAVE] = 0u;
    __syncthreads();   // the ONLY block-wide barrier in the kernel

    // ---------------- load chunk (with input gain) ----------------
    FOREACH_S(DECL_S)
    {
        const float ing = sgain[0][frame];
        const float* base = audio + (size_t)bt * S
                          + (size_t)(quarter * NCH + t) * CHUNK;
        float4 q;
        q = *(const float4*)(base +  0); s00 = q.x*ing; s01 = q.y*ing; s02 = q.z*ing; s03 = q.w*ing;
        q = *(const float4*)(base +  4); s04 = q.x*ing; s05 = q.y*ing; s06 = q.z*ing; s07 = q.w*ing;
        q = *(const float4*)(base +  8); s08 = q.x*ing; s09 = q.y*ing; s10 = q.z*ing; s11 = q.w*ing;
        q = *(const float4*)(base + 12); s12 = q.x*ing; s13 = q.y*ing; s14 = q.z*ing; s15 = q.w*ing;
    }

    // ---------------- 16 cascaded stages, barrier-free ----------------
    #pragma unroll 1
    for (int f = 0; f < NB; f++) {
        const float4 q0 = *(const float4*)&sc[f][frame][0];  // t00 t01 t10 t11
        const float4 q1 = *(const float4*)&sc[f][frame][4];  // b0 b1 c0 c1
        const float4 q2 = *(const float4*)&sc[f][frame][8];  // c2 M00 M01 M10
        const float  M11v = sc[f][frame][12];
        const float t00 = q0.x, t01 = q0.y, t10 = q0.z, t11 = q0.w;
        const float b0  = q1.x, b1  = q1.y, c0  = q1.z, c1  = q1.w;
        const float c2  = q2.x;

        // Phase A: zero-state run over own chunk -> affine constant
        float ic1 = 0.0f, ic2 = 0.0f;
        FOREACH_S(STEPA)

        // constants-only Kogge-Stone: all lanes share M=T^16, so step d
        // composes with wave-uniform M^d (register, squared in place).
        float Md00 = q2.y, Md01 = q2.z, Md10 = q2.w, Md11 = M11v;
        float Ac0 = ic1, Ac1 = ic2;
        #pragma unroll
        for (int d = 1; d < 64; d <<= 1) {
            const float lc0 = __shfl_up(Ac0, d);
            const float lc1 = __shfl_up(Ac1, d);
            if (lane >= d) {
                Ac0 = fmaf(Md00, lc0, fmaf(Md01, lc1, Ac0));
                Ac1 = fmaf(Md10, lc0, fmaf(Md11, lc1, Ac1));
            }
            const float n00 = Md00 * Md00 + Md01 * Md10;
            const float n01 = Md00 * Md01 + Md01 * Md11;
            const float n10 = Md10 * Md00 + Md11 * Md10;
            const float n11 = Md10 * Md01 + Md11 * Md11;
            Md00 = n00; Md01 = n01; Md10 = n10; Md11 = n11;
        }
        // Md = M^64 (wave aggregate matrix); Ac at lane 63 = aggregate const

        // lane-exclusive constants
        float ce0 = __shfl_up(Ac0, 1);
        float ce1 = __shfl_up(Ac1, 1);
        if (lane == 0) { ce0 = 0.0f; ce1 = 0.0f; }

        // -------- predecessor inclusive (wave-chain decoupled prefix) -----
        // Batch initial state is zero, so the predecessor's inclusive
        // CONSTANT is exactly this wave's incoming state v.
        const unsigned int tag = (unsigned int)(f + 1);
        float Mp00 = 1.0f, Mp01 = 0.0f, Mp10 = 0.0f, Mp11 = 1.0f;
        float cp0 = 0.0f, cp1 = 0.0f;
        if (wave > 0) {
            // intra-block: spin on LDS tag (wave-uniform branch), then
            // broadcast-read the 8-float slot.  s_sleep(1) throttles the DS
            // pipe so spinners can't starve the producer.
            while (__hip_atomic_load(&stag[f][wave - 1], __ATOMIC_ACQUIRE,
                                     __HIP_MEMORY_SCOPE_WORKGROUP) != tag)
                __builtin_amdgcn_s_sleep(1);
            const float4 d0 = sincl[f][wave - 1][0];
            const float4 d1 = sincl[f][wave - 1][1];
            Mp00 = d0.x; Mp01 = d0.y; Mp10 = d0.z; Mp11 = d0.w;
            cp0 = d1.x; cp1 = d1.y;
        } else if (quarter > 0) {
            // cross-block: one slot only (pred block published its INCLUSIVE)
            unsigned int* gs = ws + ((size_t)(bt * NB + f) * NBLK + (quarter - 1)) * 8;
            while (__hip_atomic_load(gs, __ATOMIC_ACQUIRE,
                                     __HIP_MEMORY_SCOPE_AGENT) != tag)
                __builtin_amdgcn_s_sleep(1);
            const float* dp = (const float*)(gs + 1);
            Mp00 = __hip_atomic_load(&dp[0], __ATOMIC_RELAXED, __HIP_MEMORY_SCOPE_AGENT);
            Mp01 = __hip_atomic_load(&dp[1], __ATOMIC_RELAXED, __HIP_MEMORY_SCOPE_AGENT);
            Mp10 = __hip_atomic_load(&dp[2], __ATOMIC_RELAXED, __HIP_MEMORY_SCOPE_AGENT);
            Mp11 = __hip_atomic_load(&dp[3], __ATOMIC_RELAXED, __HIP_MEMORY_SCOPE_AGENT);
            cp0  = __hip_atomic_load(&dp[4], __ATOMIC_RELAXED, __HIP_MEMORY_SCOPE_AGENT);
            cp1  = __hip_atomic_load(&dp[5], __ATOMIC_RELAXED, __HIP_MEMORY_SCOPE_AGENT);
        }

        // -------- compose own inclusive and publish ASAP (lane 63 holds the
        // wave-aggregate constant Ac) ---------------------------------------
        if (lane == 63) {
            const float I00 = fmaf(Md00, Mp00, Md01 * Mp10);
            const float I01 = fmaf(Md00, Mp01, Md01 * Mp11);
            const float I10 = fmaf(Md10, Mp00, Md11 * Mp10);
            const float I11 = fmaf(Md10, Mp01, Md11 * Mp11);
            const float Ic0 = fmaf(Md00, cp0, fmaf(Md01, cp1, Ac0));
            const float Ic1 = fmaf(Md10, cp0, fmaf(Md11, cp1, Ac1));
            if (wave < NWAVE - 1) {
                sincl[f][wave][0] = make_float4(I00, I01, I10, I11);
                sincl[f][wave][1] = make_float4(Ic0, Ic1, 0.0f, 0.0f);
                __hip_atomic_store(&stag[f][wave], tag, __ATOMIC_RELEASE,
                                   __HIP_MEMORY_SCOPE_WORKGROUP);
            } else if (quarter < NBLK - 1) {
                unsigned int* gs = ws + ((size_t)(bt * NB + f) * NBLK + quarter) * 8;
                float* dp = (float*)(gs + 1);
                __hip_atomic_store(&dp[0], I00, __ATOMIC_RELAXED, __HIP_MEMORY_SCOPE_AGENT);
                __hip_atomic_store(&dp[1], I01, __ATOMIC_RELAXED, __HIP_MEMORY_SCOPE_AGENT);
                __hip_atomic_store(&dp[2], I10, __ATOMIC_RELAXED, __HIP_MEMORY_SCOPE_AGENT);
                __hip_atomic_store(&dp[3], I11, __ATOMIC_RELAXED, __HIP_MEMORY_SCOPE_AGENT);
                __hip_atomic_store(&dp[4], Ic0, __ATOMIC_RELAXED, __HIP_MEMORY_SCOPE_AGENT);
                __hip_atomic_store(&dp[5], Ic1, __ATOMIC_RELAXED, __HIP_MEMORY_SCOPE_AGENT);
                __hip_atomic_store(gs, tag, __ATOMIC_RELEASE, __HIP_MEMORY_SCOPE_AGENT);
            }
        }

        // -------- distribute: incoming per-lane state = M^lane * v + ce ----
        // (powers of the same M commute; in-register binary exponentiation)
        float w0 = cp0, w1 = cp1;
        float p00 = q2.y, p01 = q2.z, p10 = q2.w, p11 = M11v;
        #pragma unroll
        for (int b = 0; b < 6; b++) {
            if (lane & (1 << b)) {
                const float nw0 = fmaf(p00, w0, p01 * w1);
                const float nw1 = fmaf(p10, w0, p11 * w1);
                w0 = nw0; w1 = nw1;
            }
            if (b < 5) {
                const float n00 = p00 * p00 + p01 * p10;
                const float n01 = p00 * p01 + p01 * p11;
                const float n10 = p10 * p00 + p11 * p10;
                const float n11 = p10 * p01 + p11 * p11;
                p00 = n00; p01 = n01; p10 = n10; p11 = n11;
            }
        }
        ic1 = w0 + ce0;
        ic2 = w1 + ce1;

        // Phase C: true run from incoming state, write outputs in place
        FOREACH_S(STEPC)
    }

    // ---------------- store (with output gain) ----------------
    {
        const float og = sgain[1][frame];
        float* base = out + (size_t)bt * S + (size_t)(quarter * NCH + t) * CHUNK;
        float4 q;
        q.x = s00*og; q.y = s01*og; q.z = s02*og; q.w = s03*og; *(float4*)(base +  0) = q;
        q.x = s04*og; q.y = s05*og; q.z = s06*og; q.w = s07*og; *(float4*)(base +  4) = q;
        q.x = s08*og; q.y = s09*og; q.z = s10*og; q.w = s11*og; *(float4*)(base +  8) = q;
        q.x = s12*og; q.y = s13*og; q.z = s14*og; q.w = s15*og; *(float4*)(base + 12) = q;
    }
}

extern "C" void kernel_launch(void* const* d_in, const int* in_sizes, int n_in,
                              void* d_out, int out_size, void* d_ws, size_t ws_size,
                              hipStream_t stream)
{
    const float* audio  = (const float*)d_in[0];
    const float* params = (const float*)d_in[1];
    float* out = (float*)d_out;
    unsigned int* ws = (unsigned int*)d_ws;
    biquad_chain_kernel<<<NBLK * NBATCH, NCH, 0, stream>>>(audio, params, out, ws);
}